// Round 6
// baseline (535.800 us; speedup 1.0000x reference)
//
#include <hip/hip_runtime.h>
#include <hip/hip_bf16.h>
#include <stdint.h>

#define B_ 2
#define S_ 2048
#define H_ 2048
#define NH_ 16
#define HD_ 128
#define M_ (B_*S_)

typedef __attribute__((ext_vector_type(8))) short short8_t;
typedef __attribute__((ext_vector_type(4))) float floatx4;
typedef __attribute__((ext_vector_type(16))) float floatx16;

__device__ __forceinline__ short f2bf(float f) {
  union { float f; uint32_t u; } x; x.f = f;
  const uint32_t u = x.u;
  return (short)((u + 0x7FFFu + ((u >> 16) & 1u)) >> 16);   // RNE
}

__device__ __forceinline__ void gload_lds16(const void* g, void* l) {
  __builtin_amdgcn_global_load_lds(
      (const __attribute__((address_space(1))) void*)g,
      (__attribute__((address_space(3))) void*)l, 16, 0, 0);
}

// ---------------------------------------------------------------- fused casts
__global__ __launch_bounds__(256)
void cast_all(const float* __restrict__ h,  const float* __restrict__ wq,
              const float* __restrict__ wk, const float* __restrict__ wv,
              const float* __restrict__ wo,
              short* __restrict__ hB,  short* __restrict__ wqB,
              short* __restrict__ wkB, short* __restrict__ wvB,
              short* __restrict__ woB) {
  const int blk = blockIdx.x;
  const float* src; short* dst; int off;
  if      (blk <  4096) { src = h;  dst = hB;  off = blk; }
  else if (blk <  6144) { src = wq; dst = wqB; off = blk - 4096; }
  else if (blk <  8192) { src = wk; dst = wkB; off = blk - 6144; }
  else if (blk < 10240) { src = wv; dst = wvB; off = blk - 8192; }
  else                  { src = wo; dst = woB; off = blk - 10240; }
  const int i = (off * 256 + threadIdx.x) * 8;
  typedef __attribute__((ext_vector_type(4))) float f4;
  const f4 a = *(const f4*)(src + i);
  const f4 b = *(const f4*)(src + i + 4);
  short8_t o;
  o[0] = f2bf(a[0]); o[1] = f2bf(a[1]); o[2] = f2bf(a[2]); o[3] = f2bf(a[3]);
  o[4] = f2bf(b[0]); o[5] = f2bf(b[1]); o[6] = f2bf(b[2]); o[7] = f2bf(b[3]);
  *(short8_t*)(dst + i) = o;
}

// ---------------------------------------------------------------- GEMM core, 128x128 tile, BK=64
// Proven R4/R5 config: ~888 TF, 0 bank conflicts.  XOR-swizzled LDS, per-lane
// swizzled global_load_lds sources.  MODE 0: bf16 out, 1: f32 out.
template<int MODE>
__device__ __forceinline__
void gemm_body(const short* __restrict__ A, const short* __restrict__ Bm,
               const float* __restrict__ bias, void* __restrict__ C,
               const int m0, const int n0, const int N, const int K) {
  __shared__ short As[128 * 64];
  __shared__ short Bs[128 * 64];
  const int tid = threadIdx.x;
  const int wv = tid >> 6, ln = tid & 63;
  const int lr = ln >> 4, lc = ln & 15;
  const int wm = (wv >> 1) * 64, wn = (wv & 1) * 64;
  const int srow = ln >> 3;
  const int sc   = (ln & 7) ^ srow;

  floatx4 acc[4][4] = {};
  const short* aP[4];
  const short* bP[4];
#pragma unroll
  for (int i = 0; i < 4; ++i)
    aP[i] = A + (size_t)(m0 + wv * 32 + i * 8 + srow) * K + sc * 8;
#pragma unroll
  for (int i = 0; i < 4; ++i)
    bP[i] = Bm + (size_t)(n0 + wv * 32 + i * 8 + srow) * K + sc * 8;
  const int sw = (lc & 7) << 3;

  for (int k0 = 0; k0 < K; k0 += 64) {
#pragma unroll
    for (int i = 0; i < 4; ++i)
      gload_lds16(aP[i] + k0, &As[(wv * 32 + i * 8) * 64]);
#pragma unroll
    for (int i = 0; i < 4; ++i)
      gload_lds16(bP[i] + k0, &Bs[(wv * 32 + i * 8) * 64]);
    __syncthreads();
#pragma unroll
    for (int ksq = 0; ksq < 2; ++ksq) {
      short8_t af[4], bf[4];
#pragma unroll
      for (int t = 0; t < 4; ++t)
        af[t] = *(const short8_t*)&As[(wm + t * 16 + lc) * 64 + ((ksq * 32 + lr * 8) ^ sw)];
#pragma unroll
      for (int t = 0; t < 4; ++t)
        bf[t] = *(const short8_t*)&Bs[(wn + t * 16 + lc) * 64 + ((ksq * 32 + lr * 8) ^ sw)];
#pragma unroll
      for (int i = 0; i < 4; ++i)
#pragma unroll
        for (int j = 0; j < 4; ++j)
          acc[i][j] = __builtin_amdgcn_mfma_f32_16x16x32_bf16(af[i], bf[j], acc[i][j], 0, 0, 0);
    }
    __syncthreads();
  }

#pragma unroll
  for (int i = 0; i < 4; ++i) {
#pragma unroll
    for (int j = 0; j < 4; ++j) {
      const int col = n0 + wn + j * 16 + lc;
      const float bv = bias[col];
#pragma unroll
      for (int r = 0; r < 4; ++r) {
        const int row = m0 + wm + i * 16 + lr * 4 + r;
        const float v = acc[i][j][r] + bv;
        if (MODE == 1) ((float*)C)[(size_t)row * N + col] = v;
        else           ((short*)C)[(size_t)row * N + col] = f2bf(v);
      }
    }
  }
}

// fused QKV: grid (48, 32); consecutive x share the A row-panel (L2 reuse)
__global__ __launch_bounds__(256)
void gemm_qkv(const short* __restrict__ A,
              const short* __restrict__ W0, const short* __restrict__ W1, const short* __restrict__ W2,
              const float* __restrict__ b0, const float* __restrict__ b1, const float* __restrict__ b2,
              short* __restrict__ C0, short* __restrict__ C1, short* __restrict__ C2) {
  const int sel = blockIdx.x >> 4;
  const short* Bm   = sel == 0 ? W0 : (sel == 1 ? W1 : W2);
  const float* bias = sel == 0 ? b0 : (sel == 1 ? b1 : b2);
  short* C          = sel == 0 ? C0 : (sel == 1 ? C1 : C2);
  gemm_body<0>(A, Bm, bias, C, blockIdx.y * 128, (blockIdx.x & 15) * 128, H_, H_);
}

__global__ __launch_bounds__(256)
void gemm_out(const short* __restrict__ A, const short* __restrict__ Bm,
              const float* __restrict__ bias, float* __restrict__ C) {
  gemm_body<1>(A, Bm, bias, C, blockIdx.y * 128, blockIdx.x * 128, H_, H_);
}

// ---------------------------------------------------------------- V transpose:
// row-major V[b*S+s][h*128+d] -> Vt[(b*16+h)*128+d][s]  (plain [bh][d][S])
__global__ __launch_bounds__(256)
void arrange_v(const short* __restrict__ V, short* __restrict__ Vt) {
  __shared__ short T[64][72];
  const int b = blockIdx.z;
  const int s0 = blockIdx.x * 64, c0 = blockIdx.y * 64;
  const int t = threadIdx.x;
  const int r = t >> 3, c8 = (t & 7) * 8;
#pragma unroll
  for (int p = 0; p < 2; ++p) {
    const int row = p * 32 + r;
    *(short8_t*)&T[row][c8] =
        *(const short8_t*)&V[(size_t)(b * S_ + s0 + row) * H_ + c0 + c8];
  }
  __syncthreads();
#pragma unroll
  for (int p = 0; p < 2; ++p) {
    const int row = p * 32 + r;
    const int gcol = c0 + row;
    const int hh = gcol >> 7, d = gcol & 127;
    short8_t o;
#pragma unroll
    for (int j = 0; j < 8; ++j) o[j] = T[c8 + j][row];
    *(short8_t*)&Vt[((size_t)(b * 16 + hh) * 128 + d) * S_ + s0 + c8] = o;
  }
}

// ---------------------------------------------------------------- flash attention, barrier-free
// 256 threads = 4 waves x 32 q-rows, 32x32x16 MFMA, fixed-scale softmax
// (verified R2-R5).  K fragments loaded per-lane straight from row-major K
// (lane=key, d contiguous 16B); V fragments from transposed Vt[bh][d][S]
// (lane=d, keys contiguous).  L1 serves the 16KB/tile working set after first
// touch; LDS holds only the wave-private P round-trip -> NO __syncthreads in
// the K-loop, waves run as independent pipelines.
__global__ __launch_bounds__(256, 2)
void attention(const short* __restrict__ Q, const short* __restrict__ Kg,
               const short* __restrict__ Vt, short* __restrict__ O) {
  __shared__ short Ps[128 * 64];   // [q][c' = keychunk ^ (q&7)], wave-private rows

  const int tid = threadIdx.x;
  const int wv = tid >> 6, ln = tid & 63;
  const int l32 = ln & 31, lh = ln >> 5;
  const int bh = blockIdx.y, b = bh >> 4, h = bh & 15;
  const int qw = blockIdx.x * 128 + wv * 32;

  const short* Qp = Q  + ((size_t)(b * S_ + qw)) * H_ + h * HD_;
  // per-lane fragment bases (advance by key0 each tile)
  const short* Kp = Kg + (size_t)(b * S_ + l32) * H_ + h * HD_ + lh * 8;   // + (key0+kh*32)*H + ksq*16
  const short* Vp = Vt + ((size_t)bh * HD_ + l32) * S_ + lh * 8;           // + dt*32*S + key0 + kf*16

  // Q A-frags: 8 frags of K=16  (A[m=l32][k=ksq*16+lh*8+j])
  short8_t qf[8];
#pragma unroll
  for (int ksq = 0; ksq < 8; ++ksq)
    qf[ksq] = *(const short8_t*)&Qp[(size_t)l32 * H_ + ksq * 16 + lh * 8];

  floatx16 oacc[4] = {};   // 4 d-tiles of 32
  float lsum[16] = {};
  const float csc = 0.08838834764831845f * 1.4426950408889634f;  // 1/sqrt(HD)*log2(e)

  const int prow = wv * 32 + l32;
  const int swp = (prow & 7) * 8;

  for (int kt = 0; kt < S_ / 64; ++kt) {
    const int key0 = kt * 64;

    // S = Q K^T : 32 q-rows x 64 keys = 2 C-tiles; kf straight from global
    floatx16 sacc[2] = {};
#pragma unroll
    for (int kh = 0; kh < 2; ++kh) {
      const short* kRow = Kp + (size_t)(key0 + kh * 32) * H_;
#pragma unroll
      for (int ksq = 0; ksq < 8; ++ksq) {
        const short8_t kf = *(const short8_t*)&kRow[ksq * 16];
        sacc[kh] = __builtin_amdgcn_mfma_f32_32x32x16_bf16(qf[ksq], kf, sacc[kh], 0, 0, 0);
      }
    }

    // fixed-scale softmax; trunc-bf16 P store, lsum consistent with stored bits
#pragma unroll
    for (int kh = 0; kh < 2; ++kh) {
#pragma unroll
      for (int r = 0; r < 16; ++r) {
        const float p = exp2f(sacc[kh][r] * csc);
        const uint32_t u = __float_as_uint(p);
        const int row = wv * 32 + (r & 3) + 8 * (r >> 2) + 4 * lh;
        const int col = kh * 32 + l32;
        Ps[row * 64 + ((((col >> 3) ^ (row & 7)) * 8) | (col & 7))] = (short)(u >> 16);
        lsum[r] += __uint_as_float(u & 0xffff0000u);
      }
    }

    // O += P V : pf from wave-private LDS (in-order same-wave), vf from global
#pragma unroll
    for (int kf = 0; kf < 4; ++kf) {
      const short8_t pf =
          *(const short8_t*)&Ps[prow * 64 + (((kf * 2 + lh) * 8) ^ swp)];
#pragma unroll
      for (int dt = 0; dt < 4; ++dt) {
        const short8_t vf =
            *(const short8_t*)&Vp[(size_t)dt * 32 * S_ + key0 + kf * 16];
        oacc[dt] = __builtin_amdgcn_mfma_f32_32x32x16_bf16(pf, vf, oacc[dt], 0, 0, 0);
      }
    }
  }

  // epilogue: reduce l across the 32 lanes sharing each row, normalize, store
  float inv[16];
#pragma unroll
  for (int r = 0; r < 16; ++r) {
    float l = lsum[r];
    l += __shfl_xor(l, 1);
    l += __shfl_xor(l, 2);
    l += __shfl_xor(l, 4);
    l += __shfl_xor(l, 8);
    l += __shfl_xor(l, 16);
    inv[r] = 1.0f / l;
  }
  short* Op = O + ((size_t)(b * S_ + qw)) * H_ + h * HD_;
#pragma unroll
  for (int dt = 0; dt < 4; ++dt)
#pragma unroll
    for (int r = 0; r < 16; ++r) {
      const int rowl = (r & 3) + 8 * (r >> 2) + 4 * lh;
      Op[(size_t)rowl * H_ + dt * 32 + l32] = f2bf(oacc[dt][r] * inv[r]);
    }
}

// ---------------------------------------------------------------- launch
extern "C" void kernel_launch(void* const* d_in, const int* in_sizes, int n_in,
                              void* d_out, int out_size, void* d_ws, size_t ws_size,
                              hipStream_t stream) {
  const float* hidden = (const float*)d_in[0];
  const float* Wq = (const float*)d_in[1];
  const float* bq = (const float*)d_in[2];
  const float* Wk = (const float*)d_in[3];
  const float* bk = (const float*)d_in[4];
  const float* Wv = (const float*)d_in[5];
  const float* bv = (const float*)d_in[6];
  const float* Wo = (const float*)d_in[7];
  const float* bo = (const float*)d_in[8];
  float* out = (float*)d_out;

  char* ws = (char*)d_ws;
  short* hB  = (short*)(ws);                       // 16 MB
  short* WqB = (short*)(ws + (16u << 20));         //  8 MB each
  short* WkB = (short*)(ws + (24u << 20));
  short* WvB = (short*)(ws + (32u << 20));
  short* WoB = (short*)(ws + (40u << 20));
  short* Qb  = (short*)(ws + (48u << 20));         // 16 MB each
  short* Kb  = (short*)(ws + (64u << 20));         // K row-major
  short* Vb  = (short*)(ws + (80u << 20));         // V row-major
  short* Vtb = (short*)(ws + (96u << 20));         // V transposed [bh][d][S]
  short* Ob  = (short*)(ws + (112u << 20));

  cast_all<<<12288, 256, 0, stream>>>(hidden, Wq, Wk, Wv, Wo, hB, WqB, WkB, WvB, WoB);

  gemm_qkv<<<dim3(48, M_ / 128), 256, 0, stream>>>(hB, WqB, WkB, WvB, bq, bk, bv, Qb, Kb, Vb);

  arrange_v<<<dim3(S_ / 64, H_ / 64, B_), 256, 0, stream>>>(Vb, Vtb);

  attention<<<dim3(S_ / 128, B_ * NH_), 256, 0, stream>>>(Qb, Kb, Vtb, Ob);

  gemm_out<<<dim3(H_ / 128, M_ / 128), 256, 0, stream>>>(Ob, WoB, bo, out);
}

// Round 7
// 435.848 us; speedup vs baseline: 1.2293x; 1.2293x over previous
//
#include <hip/hip_runtime.h>
#include <hip/hip_bf16.h>
#include <stdint.h>

#define B_ 2
#define S_ 2048
#define H_ 2048
#define NH_ 16
#define HD_ 128
#define M_ (B_*S_)

typedef __attribute__((ext_vector_type(8))) short short8_t;
typedef __attribute__((ext_vector_type(4))) float floatx4;
typedef __attribute__((ext_vector_type(16))) float floatx16;

__device__ __forceinline__ short f2bf(float f) {
  union { float f; uint32_t u; } x; x.f = f;
  const uint32_t u = x.u;
  return (short)((u + 0x7FFFu + ((u >> 16) & 1u)) >> 16);   // RNE
}

__device__ __forceinline__ void gload_lds16(const void* g, void* l) {
  __builtin_amdgcn_global_load_lds(
      (const __attribute__((address_space(1))) void*)g,
      (__attribute__((address_space(3))) void*)l, 16, 0, 0);
}

// ---------------------------------------------------------------- fused casts
__global__ __launch_bounds__(256)
void cast_all(const float* __restrict__ h,  const float* __restrict__ wq,
              const float* __restrict__ wk, const float* __restrict__ wv,
              const float* __restrict__ wo,
              short* __restrict__ hB,  short* __restrict__ wqB,
              short* __restrict__ wkB, short* __restrict__ wvB,
              short* __restrict__ woB) {
  const int blk = blockIdx.x;
  const float* src; short* dst; int off;
  if      (blk <  4096) { src = h;  dst = hB;  off = blk; }
  else if (blk <  6144) { src = wq; dst = wqB; off = blk - 4096; }
  else if (blk <  8192) { src = wk; dst = wkB; off = blk - 6144; }
  else if (blk < 10240) { src = wv; dst = wvB; off = blk - 8192; }
  else                  { src = wo; dst = woB; off = blk - 10240; }
  const int i = (off * 256 + threadIdx.x) * 8;
  typedef __attribute__((ext_vector_type(4))) float f4;
  const f4 a = *(const f4*)(src + i);
  const f4 b = *(const f4*)(src + i + 4);
  short8_t o;
  o[0] = f2bf(a[0]); o[1] = f2bf(a[1]); o[2] = f2bf(a[2]); o[3] = f2bf(a[3]);
  o[4] = f2bf(b[0]); o[5] = f2bf(b[1]); o[6] = f2bf(b[2]); o[7] = f2bf(b[3]);
  *(short8_t*)(dst + i) = o;
}

// ---------------------------------------------------------------- GEMM core, 128x128 tile, BK=64
// Proven R4/R5: ~888 TF, 0 bank conflicts.  XOR-swizzled LDS, per-lane swizzled
// global_load_lds sources.  ldk = row stride; K = k-span (for split-K).
// MODE 0: bf16 out + bias, 1: f32 out + bias, 2: f32 raw partial (no bias).
template<int MODE>
__device__ __forceinline__
void gemm_body(const short* __restrict__ A, const short* __restrict__ Bm,
               const float* __restrict__ bias, void* __restrict__ C,
               const int m0, const int n0, const int N, const int K, const int ldk) {
  __shared__ short As[128 * 64];
  __shared__ short Bs[128 * 64];
  const int tid = threadIdx.x;
  const int wv = tid >> 6, ln = tid & 63;
  const int lr = ln >> 4, lc = ln & 15;
  const int wm = (wv >> 1) * 64, wn = (wv & 1) * 64;
  const int srow = ln >> 3;
  const int sc   = (ln & 7) ^ srow;

  floatx4 acc[4][4] = {};
  const short* aP[4];
  const short* bP[4];
#pragma unroll
  for (int i = 0; i < 4; ++i)
    aP[i] = A + (size_t)(m0 + wv * 32 + i * 8 + srow) * ldk + sc * 8;
#pragma unroll
  for (int i = 0; i < 4; ++i)
    bP[i] = Bm + (size_t)(n0 + wv * 32 + i * 8 + srow) * ldk + sc * 8;
  const int sw = (lc & 7) << 3;

  for (int k0 = 0; k0 < K; k0 += 64) {
#pragma unroll
    for (int i = 0; i < 4; ++i)
      gload_lds16(aP[i] + k0, &As[(wv * 32 + i * 8) * 64]);
#pragma unroll
    for (int i = 0; i < 4; ++i)
      gload_lds16(bP[i] + k0, &Bs[(wv * 32 + i * 8) * 64]);
    __syncthreads();
#pragma unroll
    for (int ksq = 0; ksq < 2; ++ksq) {
      short8_t af[4], bf[4];
#pragma unroll
      for (int t = 0; t < 4; ++t)
        af[t] = *(const short8_t*)&As[(wm + t * 16 + lc) * 64 + ((ksq * 32 + lr * 8) ^ sw)];
#pragma unroll
      for (int t = 0; t < 4; ++t)
        bf[t] = *(const short8_t*)&Bs[(wn + t * 16 + lc) * 64 + ((ksq * 32 + lr * 8) ^ sw)];
#pragma unroll
      for (int i = 0; i < 4; ++i)
#pragma unroll
        for (int j = 0; j < 4; ++j)
          acc[i][j] = __builtin_amdgcn_mfma_f32_16x16x32_bf16(af[i], bf[j], acc[i][j], 0, 0, 0);
    }
    __syncthreads();
  }

#pragma unroll
  for (int i = 0; i < 4; ++i) {
#pragma unroll
    for (int j = 0; j < 4; ++j) {
      const int col = n0 + wn + j * 16 + lc;
      const float bv = (MODE == 2) ? 0.f : bias[col];
#pragma unroll
      for (int r = 0; r < 4; ++r) {
        const int row = m0 + wm + i * 16 + lr * 4 + r;
        const float v = acc[i][j][r] + bv;
        if (MODE == 0) ((short*)C)[(size_t)row * N + col] = f2bf(v);
        else           ((float*)C)[(size_t)row * N + col] = v;
      }
    }
  }
}

// fused QKV: grid (48, 32); consecutive x share the A row-panel (L2 reuse)
__global__ __launch_bounds__(256)
void gemm_qkv(const short* __restrict__ A,
              const short* __restrict__ W0, const short* __restrict__ W1, const short* __restrict__ W2,
              const float* __restrict__ b0, const float* __restrict__ b1, const float* __restrict__ b2,
              short* __restrict__ C0, short* __restrict__ C1, short* __restrict__ C2) {
  const int sel = blockIdx.x >> 4;
  const short* Bm   = sel == 0 ? W0 : (sel == 1 ? W1 : W2);
  const float* bias = sel == 0 ? b0 : (sel == 1 ? b1 : b2);
  short* C          = sel == 0 ? C0 : (sel == 1 ? C1 : C2);
  gemm_body<0>(A, Bm, bias, C, blockIdx.y * 128, (blockIdx.x & 15) * 128, H_, H_, H_);
}

// O-projection split-K: z = k-half; 1024 blocks (4/CU) vs 512 (2/CU starved)
__global__ __launch_bounds__(256)
void gemm_out_splitk(const short* __restrict__ A, const short* __restrict__ Bm,
                     float* __restrict__ P0, float* __restrict__ P1) {
  const int z = blockIdx.z;
  float* P = z ? P1 : P0;
  gemm_body<2>(A + z * 1024, Bm + z * 1024, nullptr, P,
               blockIdx.y * 128, blockIdx.x * 128, H_, 1024, H_);
}

// out = P0 + P1 + bias
__global__ __launch_bounds__(256)
void reduce_out(const float* __restrict__ P0, const float* __restrict__ P1,
                const float* __restrict__ bias, float* __restrict__ out) {
  typedef __attribute__((ext_vector_type(4))) float f4;
  const int i = (blockIdx.x * 256 + threadIdx.x) * 8;
  const int col = i & (H_ - 1);
  const f4 a0 = *(const f4*)(P0 + i),   a1 = *(const f4*)(P0 + i + 4);
  const f4 b0 = *(const f4*)(P1 + i),   b1 = *(const f4*)(P1 + i + 4);
  const f4 c0 = *(const f4*)(bias + col), c1 = *(const f4*)(bias + col + 4);
  *(f4*)(out + i)     = a0 + b0 + c0;
  *(f4*)(out + i + 4) = a1 + b1 + c1;
}

// ---------------------------------------------------------------- V arrange (R5-verified):
// row-major V[b*S+s][h*128+d] -> Vt[bh][kt][d][chunk c'=keychunk^(d&7)]
__global__ __launch_bounds__(256)
void arrange_v(const short* __restrict__ V, short* __restrict__ Vt) {
  __shared__ short T[64][72];
  const int b = blockIdx.z;
  const int s0 = blockIdx.x * 64, c0 = blockIdx.y * 64;
  const int t = threadIdx.x;
  const int r = t >> 3, c8 = (t & 7) * 8;
  const int kt = s0 >> 6;
#pragma unroll
  for (int p = 0; p < 2; ++p) {
    const int row = p * 32 + r;
    *(short8_t*)&T[row][c8] =
        *(const short8_t*)&V[(size_t)(b * S_ + s0 + row) * H_ + c0 + c8];
  }
  __syncthreads();
#pragma unroll
  for (int p = 0; p < 2; ++p) {
    const int row = p * 32 + r;
    const int gcol = c0 + row;
    const int hh = gcol >> 7, d = gcol & 127;
    short8_t o;
#pragma unroll
    for (int j = 0; j < 8; ++j) o[j] = T[c8 + j][row];
    const int chunk = (c8 >> 3) ^ (d & 7);
    *(short8_t*)&Vt[((((size_t)(b * 16 + hh) * 32 + kt) * 128 + d) << 6) + chunk * 8] = o;
  }
}

// ---------------------------------------------------------------- flash attention (R5 + K/V dbuf)
// 256 threads = 4 waves x 32 q-rows, 32x32x16 MFMA, fixed-scale softmax
// (verified R2-R6).  LDS-staged K/V (coalesced global_load_lds — R6 proved
// per-lane global fragments are address-divergence death).  Double-buffered
// K/V: one barrier per tile; staging loads for t+1 fly during compute of t.
__global__ __launch_bounds__(256, 2)
void attention(const short* __restrict__ Q, const short* __restrict__ Kg,
               const short* __restrict__ Vt, short* __restrict__ O) {
  __shared__ short Ks[2][64 * 128];   // [key][c' = dchunk ^ (key&7)]
  __shared__ short Vs[2][128 * 64];   // [d][c' = keychunk ^ (d&7)]
  __shared__ short Ps[128 * 64];      // [q][c' = keychunk ^ (q&7)], wave-private rows

  const int tid = threadIdx.x;
  const int wv = tid >> 6, ln = tid & 63;
  const int l32 = ln & 31, lh = ln >> 5;
  const int bh = blockIdx.y, b = bh >> 4, h = bh & 15;
  const int qw = blockIdx.x * 128 + wv * 32;

  const short* Qp  = Q  + ((size_t)(b * S_ + qw)) * H_ + h * HD_;
  const short* VtB = Vt + (size_t)bh * (S_ * HD_) + (size_t)wv * 2048 + ln * 8;

  // K staging: wave wv stages keys wv*16..wv*16+15, 4 instrs of 4 rows
  const short* kp[4];
#pragma unroll
  for (int j = 0; j < 4; ++j) {
    const int key = wv * 16 + j * 4 + (ln >> 4);
    const int sc = (ln & 15) ^ (key & 7);
    kp[j] = Kg + (size_t)(b * S_ + key) * H_ + h * HD_ + sc * 8;
  }

  // Q A-frags: 8 frags of K=16  (A[m=l32][k=ksq*16+lh*8+j])
  short8_t qf[8];
#pragma unroll
  for (int ksq = 0; ksq < 8; ++ksq)
    qf[ksq] = *(const short8_t*)&Qp[(size_t)l32 * H_ + ksq * 16 + lh * 8];

  floatx16 oacc[4] = {};   // 4 d-tiles of 32
  float lsum[16] = {};
  const float csc = 0.08838834764831845f * 1.4426950408889634f;  // 1/sqrt(HD)*log2(e)

  // prologue: stage tile 0 into buffer 0
#pragma unroll
  for (int j = 0; j < 4; ++j)
    gload_lds16(kp[j], &Ks[0][(wv * 16 + j * 4) * 128]);
#pragma unroll
  for (int j = 0; j < 4; ++j)
    gload_lds16(VtB + j * 512, &Vs[0][wv * 2048 + j * 512]);

  for (int kt = 0; kt < S_ / 64; ++kt) {
    const int cur = kt & 1;
    __syncthreads();   // drains vmcnt (stage kt landed); all waves done with buf cur^1

    if (kt + 1 < S_ / 64) {   // stage t+1 into the other buffer; lands during compute
      const size_t kadv = (size_t)(kt + 1) * 64 * H_;
#pragma unroll
      for (int j = 0; j < 4; ++j)
        gload_lds16(kp[j] + kadv, &Ks[cur ^ 1][(wv * 16 + j * 4) * 128]);
#pragma unroll
      for (int j = 0; j < 4; ++j)
        gload_lds16(VtB + (size_t)(kt + 1) * 8192 + j * 512, &Vs[cur ^ 1][wv * 2048 + j * 512]);
    }

    // S = Q K^T : 32 q-rows x 64 keys = 2 C-tiles
    floatx16 sacc[2] = {};
#pragma unroll
    for (int kh = 0; kh < 2; ++kh) {
      const int key = kh * 32 + l32;
      const int swk = (key & 7) * 8;
#pragma unroll
      for (int ksq = 0; ksq < 8; ++ksq) {
        const short8_t kf =
            *(const short8_t*)&Ks[cur][key * 128 + (((ksq * 2 + lh) * 8) ^ swk)];
        sacc[kh] = __builtin_amdgcn_mfma_f32_32x32x16_bf16(qf[ksq], kf, sacc[kh], 0, 0, 0);
      }
    }

    // fixed-scale softmax; trunc-bf16 P store, lsum consistent with stored bits
#pragma unroll
    for (int kh = 0; kh < 2; ++kh) {
#pragma unroll
      for (int r = 0; r < 16; ++r) {
        const float p = exp2f(sacc[kh][r] * csc);
        const uint32_t u = __float_as_uint(p);
        const int row = wv * 32 + (r & 3) + 8 * (r >> 2) + 4 * lh;
        const int col = kh * 32 + l32;
        Ps[row * 64 + ((((col >> 3) ^ (row & 7)) * 8) | (col & 7))] = (short)(u >> 16);
        lsum[r] += __uint_as_float(u & 0xffff0000u);
      }
    }

    // O += P V : 4 d-tiles x 4 k-frags (same-wave Ps write->read)
    const int prow = wv * 32 + l32;
    const int swp = (prow & 7) * 8;
#pragma unroll
    for (int kf = 0; kf < 4; ++kf) {
      const short8_t pf =
          *(const short8_t*)&Ps[prow * 64 + (((kf * 2 + lh) * 8) ^ swp)];
#pragma unroll
      for (int dt = 0; dt < 4; ++dt) {
        const int d = dt * 32 + l32;
        const short8_t vf =
            *(const short8_t*)&Vs[cur][d * 64 + (((kf * 2 + lh) * 8) ^ ((d & 7) * 8))];
        oacc[dt] = __builtin_amdgcn_mfma_f32_32x32x16_bf16(pf, vf, oacc[dt], 0, 0, 0);
      }
    }
  }

  // epilogue: reduce l across the 32 lanes sharing each row, normalize, store
  float inv[16];
#pragma unroll
  for (int r = 0; r < 16; ++r) {
    float l = lsum[r];
    l += __shfl_xor(l, 1);
    l += __shfl_xor(l, 2);
    l += __shfl_xor(l, 4);
    l += __shfl_xor(l, 8);
    l += __shfl_xor(l, 16);
    inv[r] = 1.0f / l;
  }
  short* Op = O + ((size_t)(b * S_ + qw)) * H_ + h * HD_;
#pragma unroll
  for (int dt = 0; dt < 4; ++dt)
#pragma unroll
    for (int r = 0; r < 16; ++r) {
      const int rowl = (r & 3) + 8 * (r >> 2) + 4 * lh;
      Op[(size_t)rowl * H_ + dt * 32 + l32] = f2bf(oacc[dt][r] * inv[r]);
    }
}

// ---------------------------------------------------------------- launch
extern "C" void kernel_launch(void* const* d_in, const int* in_sizes, int n_in,
                              void* d_out, int out_size, void* d_ws, size_t ws_size,
                              hipStream_t stream) {
  const float* hidden = (const float*)d_in[0];
  const float* Wq = (const float*)d_in[1];
  const float* bq = (const float*)d_in[2];
  const float* Wk = (const float*)d_in[3];
  const float* bk = (const float*)d_in[4];
  const float* Wv = (const float*)d_in[5];
  const float* bv = (const float*)d_in[6];
  const float* Wo = (const float*)d_in[7];
  const float* bo = (const float*)d_in[8];
  float* out = (float*)d_out;

  char* ws = (char*)d_ws;
  short* hB  = (short*)(ws);                       // 16 MB
  short* WqB = (short*)(ws + (16u << 20));         //  8 MB each
  short* WkB = (short*)(ws + (24u << 20));
  short* WvB = (short*)(ws + (32u << 20));
  short* WoB = (short*)(ws + (40u << 20));
  short* Qb  = (short*)(ws + (48u << 20));         // 16 MB each
  short* Kb  = (short*)(ws + (64u << 20));         // K row-major
  short* Vb  = (short*)(ws + (80u << 20));         // V row-major
  short* Vtb = (short*)(ws + (96u << 20));         // V arranged
  short* Ob  = (short*)(ws + (112u << 20));
  // split-K partials reuse dead Qb..Vtb region (all dead after attention)
  float* P0  = (float*)(ws + (48u << 20));         // 32 MB
  float* P1  = (float*)(ws + (80u << 20));         // 32 MB

  cast_all<<<12288, 256, 0, stream>>>(hidden, Wq, Wk, Wv, Wo, hB, WqB, WkB, WvB, WoB);

  gemm_qkv<<<dim3(48, M_ / 128), 256, 0, stream>>>(hB, WqB, WkB, WvB, bq, bk, bv, Qb, Kb, Vb);

  arrange_v<<<dim3(S_ / 64, H_ / 64, B_), 256, 0, stream>>>(Vb, Vtb);

  attention<<<dim3(S_ / 128, B_ * NH_), 256, 0, stream>>>(Qb, Kb, Vtb, Ob);

  gemm_out_splitk<<<dim3(H_ / 128, M_ / 128, 2), 256, 0, stream>>>(Ob, WoB, P0, P1);

  reduce_out<<<M_ * H_ / 2048, 256, 0, stream>>>(P0, P1, bo, out);
}

// Round 8
// 391.272 us; speedup vs baseline: 1.3694x; 1.1139x over previous
//
#include <hip/hip_runtime.h>
#include <hip/hip_bf16.h>
#include <stdint.h>

#define B_ 2
#define S_ 2048
#define H_ 2048
#define NH_ 16
#define HD_ 128
#define M_ (B_*S_)

typedef __attribute__((ext_vector_type(8))) short short8_t;
typedef __attribute__((ext_vector_type(4))) float floatx4;
typedef __attribute__((ext_vector_type(16))) float floatx16;

__device__ __forceinline__ short f2bf(float f) {
  union { float f; uint32_t u; } x; x.f = f;
  const uint32_t u = x.u;
  return (short)((u + 0x7FFFu + ((u >> 16) & 1u)) >> 16);   // RNE
}

__device__ __forceinline__ void gload_lds16(const void* g, void* l) {
  __builtin_amdgcn_global_load_lds(
      (const __attribute__((address_space(1))) void*)g,
      (__attribute__((address_space(3))) void*)l, 16, 0, 0);
}

// ---------------------------------------------------------------- fused casts
__global__ __launch_bounds__(256)
void cast_all(const float* __restrict__ h,  const float* __restrict__ wq,
              const float* __restrict__ wk, const float* __restrict__ wv,
              const float* __restrict__ wo,
              short* __restrict__ hB,  short* __restrict__ wqB,
              short* __restrict__ wkB, short* __restrict__ wvB,
              short* __restrict__ woB) {
  const int blk = blockIdx.x;
  const float* src; short* dst; int off;
  if      (blk <  4096) { src = h;  dst = hB;  off = blk; }
  else if (blk <  6144) { src = wq; dst = wqB; off = blk - 4096; }
  else if (blk <  8192) { src = wk; dst = wkB; off = blk - 6144; }
  else if (blk < 10240) { src = wv; dst = wvB; off = blk - 8192; }
  else                  { src = wo; dst = woB; off = blk - 10240; }
  const int i = (off * 256 + threadIdx.x) * 8;
  typedef __attribute__((ext_vector_type(4))) float f4;
  const f4 a = *(const f4*)(src + i);
  const f4 b = *(const f4*)(src + i + 4);
  short8_t o;
  o[0] = f2bf(a[0]); o[1] = f2bf(a[1]); o[2] = f2bf(a[2]); o[3] = f2bf(a[3]);
  o[4] = f2bf(b[0]); o[5] = f2bf(b[1]); o[6] = f2bf(b[2]); o[7] = f2bf(b[3]);
  *(short8_t*)(dst + i) = o;
}

// ---------------------------------------------------------------- GEMM core, 128x128 tile, BK=64
// Proven R4/R5: ~888 TF, 0 bank conflicts.  XOR-swizzled LDS, per-lane swizzled
// global_load_lds sources.  MODE 0: bf16 out + bias, 1: f32 out + bias.
template<int MODE>
__device__ __forceinline__
void gemm_body(const short* __restrict__ A, const short* __restrict__ Bm,
               const float* __restrict__ bias, void* __restrict__ C,
               const int m0, const int n0, const int N, const int K) {
  __shared__ short As[128 * 64];
  __shared__ short Bs[128 * 64];
  const int tid = threadIdx.x;
  const int wv = tid >> 6, ln = tid & 63;
  const int lr = ln >> 4, lc = ln & 15;
  const int wm = (wv >> 1) * 64, wn = (wv & 1) * 64;
  const int srow = ln >> 3;
  const int sc   = (ln & 7) ^ srow;

  floatx4 acc[4][4] = {};
  const short* aP[4];
  const short* bP[4];
#pragma unroll
  for (int i = 0; i < 4; ++i)
    aP[i] = A + (size_t)(m0 + wv * 32 + i * 8 + srow) * K + sc * 8;
#pragma unroll
  for (int i = 0; i < 4; ++i)
    bP[i] = Bm + (size_t)(n0 + wv * 32 + i * 8 + srow) * K + sc * 8;
  const int sw = (lc & 7) << 3;

  for (int k0 = 0; k0 < K; k0 += 64) {
#pragma unroll
    for (int i = 0; i < 4; ++i)
      gload_lds16(aP[i] + k0, &As[(wv * 32 + i * 8) * 64]);
#pragma unroll
    for (int i = 0; i < 4; ++i)
      gload_lds16(bP[i] + k0, &Bs[(wv * 32 + i * 8) * 64]);
    __syncthreads();
#pragma unroll
    for (int ksq = 0; ksq < 2; ++ksq) {
      short8_t af[4], bf[4];
#pragma unroll
      for (int t = 0; t < 4; ++t)
        af[t] = *(const short8_t*)&As[(wm + t * 16 + lc) * 64 + ((ksq * 32 + lr * 8) ^ sw)];
#pragma unroll
      for (int t = 0; t < 4; ++t)
        bf[t] = *(const short8_t*)&Bs[(wn + t * 16 + lc) * 64 + ((ksq * 32 + lr * 8) ^ sw)];
#pragma unroll
      for (int i = 0; i < 4; ++i)
#pragma unroll
        for (int j = 0; j < 4; ++j)
          acc[i][j] = __builtin_amdgcn_mfma_f32_16x16x32_bf16(af[i], bf[j], acc[i][j], 0, 0, 0);
    }
    __syncthreads();
  }

#pragma unroll
  for (int i = 0; i < 4; ++i) {
#pragma unroll
    for (int j = 0; j < 4; ++j) {
      const int col = n0 + wn + j * 16 + lc;
      const float bv = bias[col];
#pragma unroll
      for (int r = 0; r < 4; ++r) {
        const int row = m0 + wm + i * 16 + lr * 4 + r;
        const float v = acc[i][j][r] + bv;
        if (MODE == 1) ((float*)C)[(size_t)row * N + col] = v;
        else           ((short*)C)[(size_t)row * N + col] = f2bf(v);
      }
    }
  }
}

// fused QKV: grid (48, 32); consecutive x share the A row-panel (L2 reuse)
__global__ __launch_bounds__(256)
void gemm_qkv(const short* __restrict__ A,
              const short* __restrict__ W0, const short* __restrict__ W1, const short* __restrict__ W2,
              const float* __restrict__ b0, const float* __restrict__ b1, const float* __restrict__ b2,
              short* __restrict__ C0, short* __restrict__ C1, short* __restrict__ C2) {
  const int sel = blockIdx.x >> 4;
  const short* Bm   = sel == 0 ? W0 : (sel == 1 ? W1 : W2);
  const float* bias = sel == 0 ? b0 : (sel == 1 ? b1 : b2);
  short* C          = sel == 0 ? C0 : (sel == 1 ? C1 : C2);
  gemm_body<0>(A, Bm, bias, C, blockIdx.y * 128, (blockIdx.x & 15) * 128, H_, H_);
}

__global__ __launch_bounds__(256)
void gemm_out(const short* __restrict__ A, const short* __restrict__ Bm,
              const float* __restrict__ bias, float* __restrict__ C) {
  gemm_body<1>(A, Bm, bias, C, blockIdx.y * 128, blockIdx.x * 128, H_, H_);
}

// ---------------------------------------------------------------- V arrange (R5/R7-verified):
// row-major V[b*S+s][h*128+d] -> Vt[bh][kt][d][chunk c'=keychunk^(d&7)]
__global__ __launch_bounds__(256)
void arrange_v(const short* __restrict__ V, short* __restrict__ Vt) {
  __shared__ short T[64][72];
  const int b = blockIdx.z;
  const int s0 = blockIdx.x * 64, c0 = blockIdx.y * 64;
  const int t = threadIdx.x;
  const int r = t >> 3, c8 = (t & 7) * 8;
  const int kt = s0 >> 6;
#pragma unroll
  for (int p = 0; p < 2; ++p) {
    const int row = p * 32 + r;
    *(short8_t*)&T[row][c8] =
        *(const short8_t*)&V[(size_t)(b * S_ + s0 + row) * H_ + c0 + c8];
  }
  __syncthreads();
#pragma unroll
  for (int p = 0; p < 2; ++p) {
    const int row = p * 32 + r;
    const int gcol = c0 + row;
    const int hh = gcol >> 7, d = gcol & 127;
    short8_t o;
#pragma unroll
    for (int j = 0; j < 8; ++j) o[j] = T[c8 + j][row];
    const int chunk = (c8 >> 3) ^ (d & 7);
    *(short8_t*)&Vt[((((size_t)(b * 16 + hh) * 32 + kt) * 128 + d) << 6) + chunk * 8] = o;
  }
}

// ---------------------------------------------------------------- flash attention
// 256 threads = 4 waves x 32 q-rows, 32x32x16 MFMA, fixed-scale softmax
// (verified R2-R7).  NEW: S computed TRANSPOSED (S^T = K Q^T, A=K, B=Q) so P
// lives per-lane by q; the C-layout -> A-frag transform for PV is done
// IN-REGISTER via half-wave shfl_xor(32) swaps — the Ps LDS round-trip (32
// b16 writes/tile/wave, 9.4M bank conflicts) is gone.  lsum is one scalar
// per lane.  K/V double-buffered in LDS as R7.
__global__ __launch_bounds__(256, 2)
void attention(const short* __restrict__ Q, const short* __restrict__ Kg,
               const short* __restrict__ Vt, short* __restrict__ O) {
  __shared__ short Ks[2][64 * 128];   // [key][c' = dchunk ^ (key&7)]
  __shared__ short Vs[2][128 * 64];   // [d][c' = keychunk ^ (d&7)]
  __shared__ float invLds[128];

  const int tid = threadIdx.x;
  const int wv = tid >> 6, ln = tid & 63;
  const int l32 = ln & 31, lh = ln >> 5;
  const int bh = blockIdx.y, b = bh >> 4, h = bh & 15;
  const int qw = blockIdx.x * 128 + wv * 32;

  const short* Qp  = Q  + ((size_t)(b * S_ + qw)) * H_ + h * HD_;
  const short* VtB = Vt + (size_t)bh * (S_ * HD_) + (size_t)wv * 2048 + ln * 8;

  // K staging: wave wv stages keys wv*16..wv*16+15, 4 instrs of 4 rows (R7-verified)
  const short* kp[4];
#pragma unroll
  for (int j = 0; j < 4; ++j) {
    const int key = wv * 16 + j * 4 + (ln >> 4);
    const int sc = (ln & 15) ^ (key & 7);
    kp[j] = Kg + (size_t)(b * S_ + key) * H_ + h * HD_ + sc * 8;
  }

  // Q B-frags: lane n=q=l32, k(d) = ksq*16 + lh*8 + j  (same frag math as R7)
  short8_t qf[8];
#pragma unroll
  for (int ksq = 0; ksq < 8; ++ksq)
    qf[ksq] = *(const short8_t*)&Qp[(size_t)l32 * H_ + ksq * 16 + lh * 8];

  floatx16 oacc[4] = {};   // O[q][d] C-layout: col=d=l32, rows=q
  float lsum = 0.f;        // per-lane: q = l32, this lane's lh-half of keys
  const float csc = 0.08838834764831845f * 1.4426950408889634f;  // 1/sqrt(HD)*log2(e)

  // prologue: stage tile 0 into buffer 0
#pragma unroll
  for (int j = 0; j < 4; ++j)
    gload_lds16(kp[j], &Ks[0][(wv * 16 + j * 4) * 128]);
#pragma unroll
  for (int j = 0; j < 4; ++j)
    gload_lds16(VtB + j * 512, &Vs[0][wv * 2048 + j * 512]);

  for (int kt = 0; kt < S_ / 64; ++kt) {
    const int cur = kt & 1;
    __syncthreads();   // stage kt landed; all waves done with buf cur^1

    if (kt + 1 < S_ / 64) {
      const size_t kadv = (size_t)(kt + 1) * 64 * H_;
#pragma unroll
      for (int j = 0; j < 4; ++j)
        gload_lds16(kp[j] + kadv, &Ks[cur ^ 1][(wv * 16 + j * 4) * 128]);
#pragma unroll
      for (int j = 0; j < 4; ++j)
        gload_lds16(VtB + (size_t)(kt + 1) * 8192 + j * 512, &Vs[cur ^ 1][wv * 2048 + j * 512]);
    }

    // S^T = K Q^T : C[m=key][n=q]; A=K-frag (lane m=key), B=qf (lane n=q)
    floatx16 sacc[2] = {};
#pragma unroll
    for (int kh = 0; kh < 2; ++kh) {
      const int key = kh * 32 + l32;
      const int swk = (key & 7) * 8;
#pragma unroll
      for (int ksq = 0; ksq < 8; ++ksq) {
        const short8_t kf =
            *(const short8_t*)&Ks[cur][key * 128 + (((ksq * 2 + lh) * 8) ^ swk)];
        sacc[kh] = __builtin_amdgcn_mfma_f32_32x32x16_bf16(kf, qf[ksq], sacc[kh], 0, 0, 0);
      }
    }

    // fixed-scale softmax + bf16 pack + in-register transpose to P A-frags.
    // sacc reg r = key kh*32 + (r&3)+8*(r>>2)+4*lh, col q=l32.
    int pfr[4][4];
#pragma unroll
    for (int kh = 0; kh < 2; ++kh) {
      uint32_t P[8];
#pragma unroll
      for (int i = 0; i < 8; ++i) {
        const uint32_t u0 = __float_as_uint(exp2f(sacc[kh][2 * i] * csc));
        const uint32_t u1 = __float_as_uint(exp2f(sacc[kh][2 * i + 1] * csc));
        lsum += __uint_as_float(u0 & 0xffff0000u) + __uint_as_float(u1 & 0xffff0000u);
        P[i] = (u0 >> 16) | (u1 & 0xffff0000u);   // bf16 pair (k_even, k_odd), trunc
      }
      // half-wave swaps: frag kf=2kh+t = [P[t4]',P[t4+1]',P[t4+2]',P[t4+3]']
#pragma unroll
      for (int t = 0; t < 2; ++t)
#pragma unroll
        for (int j = 0; j < 2; ++j) {
          const int a = (int)P[t * 4 + j], bb = (int)P[t * 4 + j + 2];
          const int as = __shfl_xor(a, 32), bs = __shfl_xor(bb, 32);
          pfr[kh * 2 + t][j]     = lh ? bs : a;   // {A.lo, B.lo}
          pfr[kh * 2 + t][j + 2] = lh ? bb : as;  // {A.hi, B.hi}
        }
    }

    // O += P V : A=pf (regs), B=V-frag from LDS (same reads as R7)
#pragma unroll
    for (int kf = 0; kf < 4; ++kf) {
      union { int i[4]; short8_t s; } pu;
#pragma unroll
      for (int j = 0; j < 4; ++j) pu.i[j] = pfr[kf][j];
#pragma unroll
      for (int dt = 0; dt < 4; ++dt) {
        const int d = dt * 32 + l32;
        const short8_t vf =
            *(const short8_t*)&Vs[cur][d * 64 + (((kf * 2 + lh) * 8) ^ ((d & 7) * 8))];
        oacc[dt] = __builtin_amdgcn_mfma_f32_32x32x16_bf16(pu.s, vf, oacc[dt], 0, 0, 0);
      }
    }
  }

  // epilogue: total l per q = lsum(lh0) + lsum(lh1); broadcast inv via LDS
  const float l = lsum + __shfl_xor(lsum, 32);
  invLds[wv * 32 + l32] = 1.0f / l;   // both halves write same value (wave-private region)
  float inv[16];
#pragma unroll
  for (int r = 0; r < 16; ++r)
    inv[r] = invLds[wv * 32 + (r & 3) + 8 * (r >> 2) + 4 * lh];
  short* Op = O + ((size_t)(b * S_ + qw)) * H_ + h * HD_;
#pragma unroll
  for (int dt = 0; dt < 4; ++dt)
#pragma unroll
    for (int r = 0; r < 16; ++r) {
      const int rowl = (r & 3) + 8 * (r >> 2) + 4 * lh;
      Op[(size_t)rowl * H_ + dt * 32 + l32] = f2bf(oacc[dt][r] * inv[r]);
    }
}

// ---------------------------------------------------------------- launch
extern "C" void kernel_launch(void* const* d_in, const int* in_sizes, int n_in,
                              void* d_out, int out_size, void* d_ws, size_t ws_size,
                              hipStream_t stream) {
  const float* hidden = (const float*)d_in[0];
  const float* Wq = (const float*)d_in[1];
  const float* bq = (const float*)d_in[2];
  const float* Wk = (const float*)d_in[3];
  const float* bk = (const float*)d_in[4];
  const float* Wv = (const float*)d_in[5];
  const float* bv = (const float*)d_in[6];
  const float* Wo = (const float*)d_in[7];
  const float* bo = (const float*)d_in[8];
  float* out = (float*)d_out;

  char* ws = (char*)d_ws;
  short* hB  = (short*)(ws);                       // 16 MB
  short* WqB = (short*)(ws + (16u << 20));         //  8 MB each
  short* WkB = (short*)(ws + (24u << 20));
  short* WvB = (short*)(ws + (32u << 20));
  short* WoB = (short*)(ws + (40u << 20));
  short* Qb  = (short*)(ws + (48u << 20));         // 16 MB each
  short* Kb  = (short*)(ws + (64u << 20));         // K row-major
  short* Vb  = (short*)(ws + (80u << 20));         // V row-major
  short* Vtb = (short*)(ws + (96u << 20));         // V arranged
  short* Ob  = (short*)(ws + (112u << 20));

  cast_all<<<12288, 256, 0, stream>>>(hidden, Wq, Wk, Wv, Wo, hB, WqB, WkB, WvB, WoB);

  gemm_qkv<<<dim3(48, M_ / 128), 256, 0, stream>>>(hB, WqB, WkB, WvB, bq, bk, bv, Qb, Kb, Vb);

  arrange_v<<<dim3(S_ / 64, H_ / 64, B_), 256, 0, stream>>>(Vb, Vtb);

  attention<<<dim3(S_ / 128, B_ * NH_), 256, 0, stream>>>(Qb, Kb, Vtb, Ob);

  gemm_out<<<dim3(H_ / 128, M_ / 128), 256, 0, stream>>>(Ob, WoB, bo, out);
}